// Round 6
// baseline (203.833 us; speedup 1.0000x reference)
//
#include <hip/hip_runtime.h>

#define HEADS 4
#define DIM_HEAD 32
#define NB 2
#define NC 256
#define HW 4096
#define HIDDEN 128
#define NBH (NB*HEADS)
#define ROWS_TOTAL (NBH*HW)   // 32768

typedef _Float16 f16;
typedef _Float16 f16x8 __attribute__((ext_vector_type(8)));
typedef __fp16 fp16x2 __attribute__((ext_vector_type(2)));
typedef float f32x4 __attribute__((ext_vector_type(4)));

// workspace layout (bytes)  (ws_size ~= 256 MB: harness fill writes 256 MiB)
#define XT_OFF   0u                       // f16 [b][s][c256]     4 MB
#define QT_OFF   (4u<<20)                 // f16 [bh][s][d32]     2 MB
#define KT_OFF   (6u<<20)                 // f16 [bh][s][d32]     2 MB
#define VH_OFF   (8u<<20)                 // f16 [bh][d32][s]     2 MB (cols PERMUTED per 32-chunk)
#define HIDT_OFF (10u<<20)                // f16 [b][s][c128]     2 MB
#define WQH_OFF  (12u<<20)                // f16 [384][256]       192 KB
#define WOH_OFF  ((12u<<20) + (256u<<10)) // f16 [256][128]       64 KB
#define PART_OFF (13u<<20)                // f32 [split][33][32768]  34.6 MB (8 splits)
#define NSPLIT 8
#define JSPAN (HW/NSPLIT)                 // 512

__device__ __forceinline__ f16x8 ldg_f16x8(const f16* p) {
    union { uint4 u; f16x8 v; } t;
    t.u = *reinterpret_cast<const uint4*>(p);
    return t.v;
}
__device__ __forceinline__ unsigned packh2(float a, float b) {
    union { fp16x2 h; unsigned u; } t;
    t.h = __builtin_amdgcn_cvt_pkrtz(a, b);
    return t.u;
}

// ---------------------------------------------------------------------------
// wconv: permute+convert weights to f16.
// ---------------------------------------------------------------------------
__global__ __launch_bounds__(256) void wconv(const float* __restrict__ wqkv,
                                             const float* __restrict__ wout,
                                             f16* __restrict__ wqh,
                                             f16* __restrict__ woh) {
    const int tid = blockIdx.x * 256 + threadIdx.x;
    const float QSCALE = 0.17677669529663687f * 1.4426950408889634f;
    if (tid < 24576) {                       // 384*256/4
        int o_lin = tid >> 6;
        int c4 = (tid & 63) * 4;
        int which = o_lin >> 7, r = o_lin & 127;
        int head = r >> 5, d = r & 31;
        int o_g = head * 96 + d * 3 + which;
        float4 v = *reinterpret_cast<const float4*>(wqkv + o_g * 256 + c4);
        float scl = (which == 0) ? QSCALE : 1.0f;
        uint2 pv;
        pv.x = packh2(v.x * scl, v.y * scl);
        pv.y = packh2(v.z * scl, v.w * scl);
        *reinterpret_cast<uint2*>(wqh + o_lin * 256 + c4) = pv;
    } else if (tid < 24576 + 8192) {         // 256*128/4
        int t2 = tid - 24576;
        float4 v = *reinterpret_cast<const float4*>(wout + t2 * 4);
        uint2 pv;
        pv.x = packh2(v.x, v.y);
        pv.y = packh2(v.z, v.w);
        *reinterpret_cast<uint2*>(woh + t2 * 4) = pv;
    }
}

// ---------------------------------------------------------------------------
// xpose: x[b][c][s] fp32 -> XT[b][s][c] f16 (64x64 LDS-transposed tiles)
// ---------------------------------------------------------------------------
__global__ __launch_bounds__(256) void xpose(const float* __restrict__ x,
                                             f16* __restrict__ xt) {
    __shared__ float T[64][65];
    const int s0 = blockIdx.x * 64, c0 = blockIdx.y * 64, b = blockIdx.z;
    const int t = threadIdx.x;
    #pragma unroll
    for (int i = 0; i < 16; ++i) {
        int e = t + i * 256;
        int c = e >> 6, s = e & 63;
        T[c][s] = x[((size_t)(b * NC + c0 + c)) * HW + s0 + s];
    }
    __syncthreads();
    const int s = t >> 2, cg = (t & 3) * 16;
    unsigned ov[8];
    #pragma unroll
    for (int i = 0; i < 8; ++i)
        ov[i] = packh2(T[cg + 2 * i][s], T[cg + 2 * i + 1][s]);
    f16* dst = xt + ((size_t)(b * HW + s0 + s)) * 256 + c0 + cg;
    *reinterpret_cast<uint4*>(dst)     = make_uint4(ov[0], ov[1], ov[2], ov[3]);
    *reinterpret_cast<uint4*>(dst + 8) = make_uint4(ov[4], ov[5], ov[6], ov[7]);
}

// ---------------------------------------------------------------------------
// qkv_mfma: C[s][o_lin] = XT * WQH^T  (f16 MFMA, K=256).
// VH columns PERMUTED within each 32-aligned chunk so attn's post-QK
// lane-resident exp values are directly the PV B-fragment.
// ---------------------------------------------------------------------------
__global__ __launch_bounds__(256) void qkv_mfma(const f16* __restrict__ xt,
                                                const f16* __restrict__ wqh,
                                                f16* __restrict__ qt,
                                                f16* __restrict__ kt,
                                                f16* __restrict__ vh) {
    const int w = threadIdx.x >> 6, lane = threadIdx.x & 63;
    const int q15 = lane & 15, quad = lane >> 4;
    const int b = blockIdx.z;
    const int sTile = blockIdx.x * 64 + (w & 1) * 32;
    const int oTile = blockIdx.y * 64 + (w >> 1) * 32;
    const f16* A = xt + ((size_t)(b * HW + sTile)) * 256;

    f32x4 acc[2][2];
    #pragma unroll
    for (int i = 0; i < 2; ++i)
        #pragma unroll
        for (int j = 0; j < 2; ++j) acc[i][j] = (f32x4){0.f, 0.f, 0.f, 0.f};

    #pragma unroll
    for (int kc = 0; kc < 256; kc += 32) {
        f16x8 a0 = ldg_f16x8(A + (size_t)q15 * 256 + kc + quad * 8);
        f16x8 a1 = ldg_f16x8(A + (size_t)(16 + q15) * 256 + kc + quad * 8);
        f16x8 b0 = ldg_f16x8(wqh + (size_t)(oTile + q15) * 256 + kc + quad * 8);
        f16x8 b1 = ldg_f16x8(wqh + (size_t)(oTile + 16 + q15) * 256 + kc + quad * 8);
        acc[0][0] = __builtin_amdgcn_mfma_f32_16x16x32_f16(a0, b0, acc[0][0], 0, 0, 0);
        acc[0][1] = __builtin_amdgcn_mfma_f32_16x16x32_f16(a0, b1, acc[0][1], 0, 0, 0);
        acc[1][0] = __builtin_amdgcn_mfma_f32_16x16x32_f16(a1, b0, acc[1][0], 0, 0, 0);
        acc[1][1] = __builtin_amdgcn_mfma_f32_16x16x32_f16(a1, b1, acc[1][1], 0, 0, 0);
    }

    #pragma unroll
    for (int si = 0; si < 2; ++si)
        #pragma unroll
        for (int oj = 0; oj < 2; ++oj) {
            int o_lin = oTile + oj * 16 + q15;
            int which = o_lin >> 7;           // wave-uniform (tiles pure)
            int r = o_lin & 127;
            int head = r >> 5, d = r & 31;
            int bh = b * HEADS + head;
            int s2 = sTile + si * 16 + quad * 4;
            if (which == 2) {
                uint2 pv;
                pv.x = packh2(acc[si][oj][0], acc[si][oj][1]);
                pv.y = packh2(acc[si][oj][2], acc[si][oj][3]);
                int vcol = sTile + quad * 8 + si * 4;
                *reinterpret_cast<uint2*>(vh + ((size_t)(bh * 32 + d)) * HW + vcol) = pv;
            } else {
                f16* dst = (which == 0 ? qt : kt) + (size_t)bh * HW * 32;
                #pragma unroll
                for (int r2 = 0; r2 < 4; ++r2)
                    dst[(size_t)(s2 + r2) * 32 + d] = (f16)acc[si][oj][r2];
            }
        }
}

// ---------------------------------------------------------------------------
// attn_mfma: MFMA flash attention, no-max softmax, split-K over j (8 splits).
// Zero LDS; VH permutation makes exp values the PV B-fragment directly.
// XCD-AFFINITY: block L -> XCD L%8; each XCD owns one split x 8 bh
// (~512KB K/V working set, L2-resident; FETCH 17.5->6.3MB verified r5).
// NEW r6: 2-chunk ILP. Key loop unrolled x2 with double-buffered K/V regs:
// two independent QK->exp->PV chains interleave per iteration, no register
// rotation movs, no vmcnt(0) drain.  NSPLIT 4->8 doubles wave count
// (8 waves/SIMD of work) and halves per-wave chain length.
// NO launch_bounds min-occupancy arg (r2/r4: any hint -> spill storm).
// ---------------------------------------------------------------------------
#define MFMA16(A,B,C) __builtin_amdgcn_mfma_f32_16x16x32_f16(A,B,C,0,0,0)

#define LDKV(kd0,kd1,vd0,vd1,J)                                          \
    kd0 = ldg_f16x8(Kb + (size_t)((J) + q15) * 32 + quad * 8);           \
    kd1 = ldg_f16x8(Kb + (size_t)((J) + 16 + q15) * 32 + quad * 8);      \
    vd0 = ldg_f16x8(Vb + (size_t)q15 * HW + (J) + quad * 8);             \
    vd1 = ldg_f16x8(Vb + (size_t)(16 + q15) * HW + (J) + quad * 8);

#define CHUNK(kf0_,kf1_,vf0_,vf1_)                                       \
    {                                                                    \
        const f32x4 z = {0.f, 0.f, 0.f, 0.f};                            \
        f32x4 s0a = MFMA16(kf0_, qf0, z);                                \
        f32x4 s1a = MFMA16(kf1_, qf0, z);                                \
        f32x4 s0b = MFMA16(kf0_, qf1, z);                                \
        f32x4 s1b = MFMA16(kf1_, qf1, z);                                \
        float ea[8], eb[8];                                              \
        _Pragma("unroll")                                                \
        for (int r = 0; r < 4; ++r) {                                    \
            ea[r]   = __builtin_amdgcn_exp2f(s0a[r]);                    \
            ea[4+r] = __builtin_amdgcn_exp2f(s1a[r]);                    \
            eb[r]   = __builtin_amdgcn_exp2f(s0b[r]);                    \
            eb[4+r] = __builtin_amdgcn_exp2f(s1b[r]);                    \
        }                                                                \
        l0 += (ea[0]+ea[1])+(ea[2]+ea[3])+(ea[4]+ea[5])+(ea[6]+ea[7]);   \
        l1 += (eb[0]+eb[1])+(eb[2]+eb[3])+(eb[4]+eb[5])+(eb[6]+eb[7]);   \
        union { unsigned u[4]; f16x8 v; } pa, pb;                        \
        pa.u[0] = packh2(ea[0], ea[1]); pa.u[1] = packh2(ea[2], ea[3]);  \
        pa.u[2] = packh2(ea[4], ea[5]); pa.u[3] = packh2(ea[6], ea[7]);  \
        pb.u[0] = packh2(eb[0], eb[1]); pb.u[1] = packh2(eb[2], eb[3]);  \
        pb.u[2] = packh2(eb[4], eb[5]); pb.u[3] = packh2(eb[6], eb[7]);  \
        acc[0][0] = MFMA16(vf0_, pa.v, acc[0][0]);                       \
        acc[0][1] = MFMA16(vf1_, pa.v, acc[0][1]);                       \
        acc[1][0] = MFMA16(vf0_, pb.v, acc[1][0]);                       \
        acc[1][1] = MFMA16(vf1_, pb.v, acc[1][1]);                       \
    }

__global__ __launch_bounds__(256) void attn_mfma(const f16* __restrict__ qt,
                                                 const f16* __restrict__ kt,
                                                 const f16* __restrict__ vh,
                                                 float* __restrict__ part) {
    const int w    = threadIdx.x >> 6;
    const int lane = threadIdx.x & 63;
    const int q15  = lane & 15;
    const int quad = lane >> 4;

    const int L    = blockIdx.x;          // 0..2047
    const int xcd  = L & 7;               // dispatch round-robin -> XCD id
    const int slot = L >> 3;              // 0..255 within XCD
    const int combo = xcd * 8 + (slot >> 5);   // 0..63 = (split,bh)
    const int qblk  = slot & 31;
    const int bh    = combo & 7;
    const int split = combo >> 3;              // == xcd
    const int qbase = (qblk * 4 + w) * 32;

    const f16* Qb = qt + (size_t)bh * HW * 32;
    const f16* Kb = kt + (size_t)bh * HW * 32;
    const f16* Vb = vh + (size_t)bh * 32 * HW;

    f16x8 qf0 = ldg_f16x8(Qb + (size_t)(qbase + q15) * 32 + quad * 8);
    f16x8 qf1 = ldg_f16x8(Qb + (size_t)(qbase + 16 + q15) * 32 + quad * 8);

    f32x4 acc[2][2];
    #pragma unroll
    for (int a = 0; a < 2; ++a)
        #pragma unroll
        for (int b2 = 0; b2 < 2; ++b2)
            acc[a][b2] = (f32x4){0.f, 0.f, 0.f, 0.f};
    float l0 = 0.f, l1 = 0.f;

    const int j0 = split * JSPAN;
    f16x8 ka0, ka1, va0, va1, kb0, kb1, vb0, vb1;
    LDKV(ka0, ka1, va0, va1, j0);
    LDKV(kb0, kb1, vb0, vb1, j0 + 32);

    for (int jc = 0; jc < JSPAN; jc += 64) {
        CHUNK(ka0, ka1, va0, va1);
        LDKV(ka0, ka1, va0, va1, j0 + jc + 64);   // last-iter prefetch reads
        CHUNK(kb0, kb1, vb0, vb1);                // past span: valid ws mem,
        LDKV(kb0, kb1, vb0, vb1, j0 + jc + 96);   // values unused
    }

    float* P = part + (size_t)split * 33 * ROWS_TOTAL;
    #pragma unroll
    for (int qb = 0; qb < 2; ++qb) {
        float lv = qb ? l1 : l0;
        lv += __shfl_xor(lv, 16, 64);
        lv += __shfl_xor(lv, 32, 64);
        const int grow = bh * HW + qbase + qb * 16 + q15;
        if (quad == 0) P[grow] = lv;
        #pragma unroll
        for (int t = 0; t < 2; ++t)
            #pragma unroll
            for (int r = 0; r < 4; ++r) {
                int d = t * 16 + quad * 4 + r;
                P[(size_t)(1 + d) * ROWS_TOTAL + grow] = acc[qb][t][r];
            }
    }
}

// ---------------------------------------------------------------------------
// attn_merge: sum NSPLIT additive splits, normalize, write HIDT f16
// ---------------------------------------------------------------------------
__global__ __launch_bounds__(256) void attn_merge(const float* __restrict__ part,
                                                  f16* __restrict__ hidt) {
    const int grow = blockIdx.x * 256 + threadIdx.x;   // 0..32767
    float l = 0.f;
    #pragma unroll
    for (int sp = 0; sp < NSPLIT; ++sp)
        l += part[(size_t)sp * 33 * ROWS_TOTAL + grow];
    const float inv = 1.0f / l;
    const int bh = grow >> 12, s = grow & 4095;
    const int b = bh >> 2, h = bh & 3;

    unsigned ov[16];
    #pragma unroll
    for (int d2 = 0; d2 < 16; ++d2) {
        float o0 = 0.f, o1 = 0.f;
        #pragma unroll
        for (int sp = 0; sp < NSPLIT; ++sp) {
            const float* P = part + (size_t)sp * 33 * ROWS_TOTAL + grow;
            o0 += P[(size_t)(1 + 2 * d2) * ROWS_TOTAL];
            o1 += P[(size_t)(2 + 2 * d2) * ROWS_TOTAL];
        }
        ov[d2] = packh2(o0 * inv, o1 * inv);
    }
    f16* dst = hidt + ((size_t)(b * HW + s)) * 128 + h * 32;
    *reinterpret_cast<uint4*>(dst)      = make_uint4(ov[0],  ov[1],  ov[2],  ov[3]);
    *reinterpret_cast<uint4*>(dst + 8)  = make_uint4(ov[4],  ov[5],  ov[6],  ov[7]);
    *reinterpret_cast<uint4*>(dst + 16) = make_uint4(ov[8],  ov[9],  ov[10], ov[11]);
    *reinterpret_cast<uint4*>(dst + 24) = make_uint4(ov[12], ov[13], ov[14], ov[15]);
}

// ---------------------------------------------------------------------------
// outp_mfma: out[b][o][s] = HIDT * WOH^T + bias  (f16 MFMA, K=128, fp32 out)
// ---------------------------------------------------------------------------
__global__ __launch_bounds__(256) void outp_mfma(const f16* __restrict__ hidt,
                                                 const f16* __restrict__ woh,
                                                 const float* __restrict__ bout,
                                                 float* __restrict__ out) {
    const int w = threadIdx.x >> 6, lane = threadIdx.x & 63;
    const int q15 = lane & 15, quad = lane >> 4;
    const int b = blockIdx.z;
    const int sTile = blockIdx.x * 64 + (w & 1) * 32;
    const int oTile = blockIdx.y * 64 + (w >> 1) * 32;
    const f16* A = hidt + ((size_t)(b * HW + sTile)) * 128;

    f32x4 acc[2][2];
    #pragma unroll
    for (int i = 0; i < 2; ++i)
        #pragma unroll
        for (int j = 0; j < 2; ++j) acc[i][j] = (f32x4){0.f, 0.f, 0.f, 0.f};

    #pragma unroll
    for (int kc = 0; kc < 128; kc += 32) {
        f16x8 a0 = ldg_f16x8(A + (size_t)q15 * 128 + kc + quad * 8);
        f16x8 a1 = ldg_f16x8(A + (size_t)(16 + q15) * 128 + kc + quad * 8);
        f16x8 b0 = ldg_f16x8(woh + (size_t)(oTile + q15) * 128 + kc + quad * 8);
        f16x8 b1 = ldg_f16x8(woh + (size_t)(oTile + 16 + q15) * 128 + kc + quad * 8);
        acc[0][0] = __builtin_amdgcn_mfma_f32_16x16x32_f16(a0, b0, acc[0][0], 0, 0, 0);
        acc[0][1] = __builtin_amdgcn_mfma_f32_16x16x32_f16(a0, b1, acc[0][1], 0, 0, 0);
        acc[1][0] = __builtin_amdgcn_mfma_f32_16x16x32_f16(a1, b0, acc[1][0], 0, 0, 0);
        acc[1][1] = __builtin_amdgcn_mfma_f32_16x16x32_f16(a1, b1, acc[1][1], 0, 0, 0);
    }

    #pragma unroll
    for (int oj = 0; oj < 2; ++oj) {
        const int o = oTile + oj * 16 + q15;
        const float bias = bout[o];
        #pragma unroll
        for (int si = 0; si < 2; ++si) {
            const int s2 = sTile + si * 16 + quad * 4;
            float4 v = make_float4(acc[si][oj][0] + bias, acc[si][oj][1] + bias,
                                   acc[si][oj][2] + bias, acc[si][oj][3] + bias);
            *reinterpret_cast<float4*>(out + ((size_t)(b * NC + o)) * HW + s2) = v;
        }
    }
}

// ---------------------------------------------------------------------------
extern "C" void kernel_launch(void* const* d_in, const int* in_sizes, int n_in,
                              void* d_out, int out_size, void* d_ws, size_t ws_size,
                              hipStream_t stream) {
    const float* x    = (const float*)d_in[0];
    const float* wqkv = (const float*)d_in[1];
    const float* wout = (const float*)d_in[2];
    const float* bout = (const float*)d_in[3];
    float* out = (float*)d_out;
    char* wsb  = (char*)d_ws;

    f16*   XT   = (f16*)(wsb + XT_OFF);
    f16*   QT   = (f16*)(wsb + QT_OFF);
    f16*   KT   = (f16*)(wsb + KT_OFF);
    f16*   VH   = (f16*)(wsb + VH_OFF);
    f16*   HIDT = (f16*)(wsb + HIDT_OFF);
    f16*   WQH  = (f16*)(wsb + WQH_OFF);
    f16*   WOH  = (f16*)(wsb + WOH_OFF);
    float* PART = (float*)(wsb + PART_OFF);

    wconv    <<<dim3(128), 256, 0, stream>>>(wqkv, wout, WQH, WOH);
    xpose    <<<dim3(64, 4, NB), 256, 0, stream>>>(x, XT);
    qkv_mfma <<<dim3(64, 6, NB), 256, 0, stream>>>(XT, WQH, QT, KT, VH);
    attn_mfma<<<dim3(2048), 256, 0, stream>>>(QT, KT, VH, PART);
    attn_merge<<<dim3(128), 256, 0, stream>>>(PART, HIDT);
    outp_mfma<<<dim3(64, 4, NB), 256, 0, stream>>>(HIDT, WOH, bout, out);
}

// Round 7
// 149.665 us; speedup vs baseline: 1.3619x; 1.3619x over previous
//
#include <hip/hip_runtime.h>

#define HEADS 4
#define DIM_HEAD 32
#define NB 2
#define NC 256
#define HW 4096
#define HIDDEN 128
#define NBH (NB*HEADS)
#define ROWS_TOTAL (NBH*HW)   // 32768

typedef _Float16 f16;
typedef _Float16 f16x8 __attribute__((ext_vector_type(8)));
typedef __fp16 fp16x2 __attribute__((ext_vector_type(2)));
typedef float f32x4 __attribute__((ext_vector_type(4)));

// workspace layout (bytes)
#define XT_OFF   0u                       // f16 [b][s][c256]     4 MB
#define QT_OFF   (4u<<20)                 // f16 [bh][s][d32]     2 MB
#define KT_OFF   (6u<<20)                 // f16 [bh][s][d32]     2 MB
#define VH_OFF   (8u<<20)                 // f16 [bh][d32][s]     2 MB (cols PERMUTED per 32-chunk)
#define HIDT_OFF (10u<<20)                // f16 [b][s][c128]     2 MB
#define WQH_OFF  (12u<<20)                // f16 [384][256]       192 KB
#define WOH_OFF  ((12u<<20) + (256u<<10)) // f16 [256][128]       64 KB
#define PART_OFF (13u<<20)                // f32 [split][33][32768]  17.3 MB
#define NSPLIT 4
#define JSPAN (HW/NSPLIT)                 // 1024

__device__ __forceinline__ f16x8 ldg_f16x8(const f16* p) {
    union { uint4 u; f16x8 v; } t;
    t.u = *reinterpret_cast<const uint4*>(p);
    return t.v;
}
__device__ __forceinline__ unsigned packh2(float a, float b) {
    union { fp16x2 h; unsigned u; } t;
    t.h = __builtin_amdgcn_cvt_pkrtz(a, b);
    return t.u;
}

// ---------------------------------------------------------------------------
// wconv: permute+convert weights to f16.
// ---------------------------------------------------------------------------
__global__ __launch_bounds__(256) void wconv(const float* __restrict__ wqkv,
                                             const float* __restrict__ wout,
                                             f16* __restrict__ wqh,
                                             f16* __restrict__ woh) {
    const int tid = blockIdx.x * 256 + threadIdx.x;
    const float QSCALE = 0.17677669529663687f * 1.4426950408889634f;
    if (tid < 24576) {                       // 384*256/4
        int o_lin = tid >> 6;
        int c4 = (tid & 63) * 4;
        int which = o_lin >> 7, r = o_lin & 127;
        int head = r >> 5, d = r & 31;
        int o_g = head * 96 + d * 3 + which;
        float4 v = *reinterpret_cast<const float4*>(wqkv + o_g * 256 + c4);
        float scl = (which == 0) ? QSCALE : 1.0f;
        uint2 pv;
        pv.x = packh2(v.x * scl, v.y * scl);
        pv.y = packh2(v.z * scl, v.w * scl);
        *reinterpret_cast<uint2*>(wqh + o_lin * 256 + c4) = pv;
    } else if (tid < 24576 + 8192) {         // 256*128/4
        int t2 = tid - 24576;
        float4 v = *reinterpret_cast<const float4*>(wout + t2 * 4);
        uint2 pv;
        pv.x = packh2(v.x, v.y);
        pv.y = packh2(v.z, v.w);
        *reinterpret_cast<uint2*>(woh + t2 * 4) = pv;
    }
}

// ---------------------------------------------------------------------------
// xpose: x[b][c][s] fp32 -> XT[b][s][c] f16 (64x64 LDS-transposed tiles)
// ---------------------------------------------------------------------------
__global__ __launch_bounds__(256) void xpose(const float* __restrict__ x,
                                             f16* __restrict__ xt) {
    __shared__ float T[64][65];
    const int s0 = blockIdx.x * 64, c0 = blockIdx.y * 64, b = blockIdx.z;
    const int t = threadIdx.x;
    #pragma unroll
    for (int i = 0; i < 16; ++i) {
        int e = t + i * 256;
        int c = e >> 6, s = e & 63;
        T[c][s] = x[((size_t)(b * NC + c0 + c)) * HW + s0 + s];
    }
    __syncthreads();
    const int s = t >> 2, cg = (t & 3) * 16;
    unsigned ov[8];
    #pragma unroll
    for (int i = 0; i < 8; ++i)
        ov[i] = packh2(T[cg + 2 * i][s], T[cg + 2 * i + 1][s]);
    f16* dst = xt + ((size_t)(b * HW + s0 + s)) * 256 + c0 + cg;
    *reinterpret_cast<uint4*>(dst)     = make_uint4(ov[0], ov[1], ov[2], ov[3]);
    *reinterpret_cast<uint4*>(dst + 8) = make_uint4(ov[4], ov[5], ov[6], ov[7]);
}

// ---------------------------------------------------------------------------
// qkv_mfma: C[s][o_lin] = XT * WQH^T  (f16 MFMA, K=256).
// VH columns PERMUTED within each 32-aligned chunk so attn's post-QK
// lane-resident exp values are directly the PV B-fragment.
// ---------------------------------------------------------------------------
__global__ __launch_bounds__(256) void qkv_mfma(const f16* __restrict__ xt,
                                                const f16* __restrict__ wqh,
                                                f16* __restrict__ qt,
                                                f16* __restrict__ kt,
                                                f16* __restrict__ vh) {
    const int w = threadIdx.x >> 6, lane = threadIdx.x & 63;
    const int q15 = lane & 15, quad = lane >> 4;
    const int b = blockIdx.z;
    const int sTile = blockIdx.x * 64 + (w & 1) * 32;
    const int oTile = blockIdx.y * 64 + (w >> 1) * 32;
    const f16* A = xt + ((size_t)(b * HW + sTile)) * 256;

    f32x4 acc[2][2];
    #pragma unroll
    for (int i = 0; i < 2; ++i)
        #pragma unroll
        for (int j = 0; j < 2; ++j) acc[i][j] = (f32x4){0.f, 0.f, 0.f, 0.f};

    #pragma unroll
    for (int kc = 0; kc < 256; kc += 32) {
        f16x8 a0 = ldg_f16x8(A + (size_t)q15 * 256 + kc + quad * 8);
        f16x8 a1 = ldg_f16x8(A + (size_t)(16 + q15) * 256 + kc + quad * 8);
        f16x8 b0 = ldg_f16x8(wqh + (size_t)(oTile + q15) * 256 + kc + quad * 8);
        f16x8 b1 = ldg_f16x8(wqh + (size_t)(oTile + 16 + q15) * 256 + kc + quad * 8);
        acc[0][0] = __builtin_amdgcn_mfma_f32_16x16x32_f16(a0, b0, acc[0][0], 0, 0, 0);
        acc[0][1] = __builtin_amdgcn_mfma_f32_16x16x32_f16(a0, b1, acc[0][1], 0, 0, 0);
        acc[1][0] = __builtin_amdgcn_mfma_f32_16x16x32_f16(a1, b0, acc[1][0], 0, 0, 0);
        acc[1][1] = __builtin_amdgcn_mfma_f32_16x16x32_f16(a1, b1, acc[1][1], 0, 0, 0);
    }

    #pragma unroll
    for (int si = 0; si < 2; ++si)
        #pragma unroll
        for (int oj = 0; oj < 2; ++oj) {
            int o_lin = oTile + oj * 16 + q15;
            int which = o_lin >> 7;           // wave-uniform (tiles pure)
            int r = o_lin & 127;
            int head = r >> 5, d = r & 31;
            int bh = b * HEADS + head;
            int s2 = sTile + si * 16 + quad * 4;
            if (which == 2) {
                uint2 pv;
                pv.x = packh2(acc[si][oj][0], acc[si][oj][1]);
                pv.y = packh2(acc[si][oj][2], acc[si][oj][3]);
                int vcol = sTile + quad * 8 + si * 4;
                *reinterpret_cast<uint2*>(vh + ((size_t)(bh * 32 + d)) * HW + vcol) = pv;
            } else {
                f16* dst = (which == 0 ? qt : kt) + (size_t)bh * HW * 32;
                #pragma unroll
                for (int r2 = 0; r2 < 4; ++r2)
                    dst[(size_t)(s2 + r2) * 32 + d] = (f16)acc[si][oj][r2];
            }
        }
}

// ---------------------------------------------------------------------------
// attn_mfma: MFMA flash attention, no-max softmax, split-K over j (4 splits),
// explicit next-chunk prefetch.  Per wave: 32 q-rows x JSPAN keys.
// Zero LDS; VH permutation makes exp values the PV B-fragment directly.
// XCD-AFFINITY: block L -> XCD L%8; each XCD owns 4 (split,bh) combos
// (~512KB K/V working set, L2-resident; FETCH 17.5->6.3MB verified r5).
// NO launch_bounds min-occupancy arg (r2/r4: any hint -> spill storm).
// This is the r5-measured version (58.3us), reverted from r6's unvalidated
// 2-chunk/8-split variant to isolate the merge fix.
// ---------------------------------------------------------------------------
__global__ __launch_bounds__(256) void attn_mfma(const f16* __restrict__ qt,
                                                 const f16* __restrict__ kt,
                                                 const f16* __restrict__ vh,
                                                 float* __restrict__ part) {
    const int w    = threadIdx.x >> 6;
    const int lane = threadIdx.x & 63;
    const int q15  = lane & 15;
    const int quad = lane >> 4;

    const int L    = blockIdx.x;          // 0..1023
    const int xcd  = L & 7;               // dispatch round-robin -> XCD id
    const int slot = L >> 3;              // 0..127 within XCD
    const int combo = xcd * 4 + (slot >> 5);   // 0..31 = (split,bh)
    const int qblk  = slot & 31;
    const int bh    = combo & 7;
    const int split = combo >> 3;
    const int qbase = (qblk * 4 + w) * 32;

    const f16* Qb = qt + (size_t)bh * HW * 32;
    const f16* Kb = kt + (size_t)bh * HW * 32;
    const f16* Vb = vh + (size_t)bh * 32 * HW;

    f16x8 qf0 = ldg_f16x8(Qb + (size_t)(qbase + q15) * 32 + quad * 8);
    f16x8 qf1 = ldg_f16x8(Qb + (size_t)(qbase + 16 + q15) * 32 + quad * 8);

    f32x4 acc[2][2];
    #pragma unroll
    for (int a = 0; a < 2; ++a)
        #pragma unroll
        for (int b2 = 0; b2 < 2; ++b2)
            acc[a][b2] = (f32x4){0.f, 0.f, 0.f, 0.f};
    float l0 = 0.f, l1 = 0.f;

    const int j0 = split * JSPAN;
    f16x8 kf0 = ldg_f16x8(Kb + (size_t)(j0 + q15) * 32 + quad * 8);
    f16x8 kf1 = ldg_f16x8(Kb + (size_t)(j0 + 16 + q15) * 32 + quad * 8);
    f16x8 vf0 = ldg_f16x8(Vb + (size_t)q15 * HW + j0 + quad * 8);
    f16x8 vf1 = ldg_f16x8(Vb + (size_t)(16 + q15) * HW + j0 + quad * 8);

    for (int jc = 0; jc < JSPAN; jc += 32) {
        const int jn = j0 + jc + 32;   // prefetch (last iter reads past span:
                                       // lands in adjacent ws region, unused)
        f16x8 nk0 = ldg_f16x8(Kb + (size_t)(jn + q15) * 32 + quad * 8);
        f16x8 nk1 = ldg_f16x8(Kb + (size_t)(jn + 16 + q15) * 32 + quad * 8);
        f16x8 nv0 = ldg_f16x8(Vb + (size_t)q15 * HW + jn + quad * 8);
        f16x8 nv1 = ldg_f16x8(Vb + (size_t)(16 + q15) * HW + jn + quad * 8);

        const f32x4 z = {0.f, 0.f, 0.f, 0.f};
        #pragma unroll
        for (int qb = 0; qb < 2; ++qb) {
            f16x8 qf = qb ? qf1 : qf0;
            // s0[r] = S[key = quad*4+r][q=q15], s1[r] = S[key = 16+quad*4+r][q]
            f32x4 s0 = __builtin_amdgcn_mfma_f32_16x16x32_f16(kf0, qf, z, 0, 0, 0);
            f32x4 s1 = __builtin_amdgcn_mfma_f32_16x16x32_f16(kf1, qf, z, 0, 0, 0);
            float e[8];
            #pragma unroll
            for (int r = 0; r < 4; ++r) {
                e[r]     = __builtin_amdgcn_exp2f(s0[r]);
                e[4 + r] = __builtin_amdgcn_exp2f(s1[r]);
            }
            float ls = (e[0] + e[1]) + (e[2] + e[3]) + (e[4] + e[5]) + (e[6] + e[7]);
            if (qb) l1 += ls; else l0 += ls;
            // VH column permutation makes this lane's 8 exp values exactly
            // B[k = quad*8 + 0..7][q=q15] for the PV MFMA: pack and go.
            union { unsigned u[4]; f16x8 v; } pu;
            pu.u[0] = packh2(e[0], e[1]);
            pu.u[1] = packh2(e[2], e[3]);
            pu.u[2] = packh2(e[4], e[5]);
            pu.u[3] = packh2(e[6], e[7]);
            acc[qb][0] = __builtin_amdgcn_mfma_f32_16x16x32_f16(vf0, pu.v, acc[qb][0], 0, 0, 0);
            acc[qb][1] = __builtin_amdgcn_mfma_f32_16x16x32_f16(vf1, pu.v, acc[qb][1], 0, 0, 0);
        }
        kf0 = nk0; kf1 = nk1; vf0 = nv0; vf1 = nv1;
    }

    float* P = part + (size_t)split * 33 * ROWS_TOTAL;
    #pragma unroll
    for (int qb = 0; qb < 2; ++qb) {
        float lv = qb ? l1 : l0;
        lv += __shfl_xor(lv, 16, 64);
        lv += __shfl_xor(lv, 32, 64);
        const int grow = bh * HW + qbase + qb * 16 + q15;
        if (quad == 0) P[grow] = lv;
        #pragma unroll
        for (int t = 0; t < 2; ++t)
            #pragma unroll
            for (int r = 0; r < 4; ++r) {
                int d = t * 16 + quad * 4 + r;
                P[(size_t)(1 + d) * ROWS_TOTAL + grow] = acc[qb][t][r];
            }
    }
}

// ---------------------------------------------------------------------------
// attn_merge: sum NSPLIT additive splits, normalize, write HIDT f16.
// r7 FIX: r6 showed merge was the hidden #1 cost (64us, Occupancy 4.9%,
// 300 GB/s): 128 blocks left half the CUs idle and 264 loads/thread were
// latency-serialized.  Now thread = (grow, dquad): 131072 threads / 512
// blocks (2/CU), 36 independent 4B loads + one coalesced 16B write each.
// ---------------------------------------------------------------------------
__global__ __launch_bounds__(256) void attn_merge(const float* __restrict__ part,
                                                  f16* __restrict__ hidt) {
    const int t = blockIdx.x * 256 + threadIdx.x;      // 0..131071
    const int grow = t >> 2;                           // 0..32767
    const int dq   = t & 3;                            // 0..3 (8 d values each)
    float l = 0.f;
    #pragma unroll
    for (int sp = 0; sp < NSPLIT; ++sp)
        l += part[(size_t)sp * 33 * ROWS_TOTAL + grow];
    const float inv = 1.0f / l;
    const int bh = grow >> 12, s = grow & 4095;
    const int b = bh >> 2, h = bh & 3;

    unsigned ov[4];
    #pragma unroll
    for (int i = 0; i < 4; ++i) {
        const int d2 = dq * 4 + i;
        float o0 = 0.f, o1 = 0.f;
        #pragma unroll
        for (int sp = 0; sp < NSPLIT; ++sp) {
            const float* P = part + (size_t)sp * 33 * ROWS_TOTAL + grow;
            o0 += P[(size_t)(1 + 2 * d2) * ROWS_TOTAL];
            o1 += P[(size_t)(2 + 2 * d2) * ROWS_TOTAL];
        }
        ov[i] = packh2(o0 * inv, o1 * inv);
    }
    f16* dst = hidt + ((size_t)(b * HW + s)) * 128 + h * 32 + dq * 8;
    *reinterpret_cast<uint4*>(dst) = make_uint4(ov[0], ov[1], ov[2], ov[3]);
}

// ---------------------------------------------------------------------------
// outp_mfma: out[b][o][s] = HIDT * WOH^T + bias  (f16 MFMA, K=128, fp32 out)
// ---------------------------------------------------------------------------
__global__ __launch_bounds__(256) void outp_mfma(const f16* __restrict__ hidt,
                                                 const f16* __restrict__ woh,
                                                 const float* __restrict__ bout,
                                                 float* __restrict__ out) {
    const int w = threadIdx.x >> 6, lane = threadIdx.x & 63;
    const int q15 = lane & 15, quad = lane >> 4;
    const int b = blockIdx.z;
    const int sTile = blockIdx.x * 64 + (w & 1) * 32;
    const int oTile = blockIdx.y * 64 + (w >> 1) * 32;
    const f16* A = hidt + ((size_t)(b * HW + sTile)) * 128;

    f32x4 acc[2][2];
    #pragma unroll
    for (int i = 0; i < 2; ++i)
        #pragma unroll
        for (int j = 0; j < 2; ++j) acc[i][j] = (f32x4){0.f, 0.f, 0.f, 0.f};

    #pragma unroll
    for (int kc = 0; kc < 128; kc += 32) {
        f16x8 a0 = ldg_f16x8(A + (size_t)q15 * 128 + kc + quad * 8);
        f16x8 a1 = ldg_f16x8(A + (size_t)(16 + q15) * 128 + kc + quad * 8);
        f16x8 b0 = ldg_f16x8(woh + (size_t)(oTile + q15) * 128 + kc + quad * 8);
        f16x8 b1 = ldg_f16x8(woh + (size_t)(oTile + 16 + q15) * 128 + kc + quad * 8);
        acc[0][0] = __builtin_amdgcn_mfma_f32_16x16x32_f16(a0, b0, acc[0][0], 0, 0, 0);
        acc[0][1] = __builtin_amdgcn_mfma_f32_16x16x32_f16(a0, b1, acc[0][1], 0, 0, 0);
        acc[1][0] = __builtin_amdgcn_mfma_f32_16x16x32_f16(a1, b0, acc[1][0], 0, 0, 0);
        acc[1][1] = __builtin_amdgcn_mfma_f32_16x16x32_f16(a1, b1, acc[1][1], 0, 0, 0);
    }

    #pragma unroll
    for (int oj = 0; oj < 2; ++oj) {
        const int o = oTile + oj * 16 + q15;
        const float bias = bout[o];
        #pragma unroll
        for (int si = 0; si < 2; ++si) {
            const int s2 = sTile + si * 16 + quad * 4;
            float4 v = make_float4(acc[si][oj][0] + bias, acc[si][oj][1] + bias,
                                   acc[si][oj][2] + bias, acc[si][oj][3] + bias);
            *reinterpret_cast<float4*>(out + ((size_t)(b * NC + o)) * HW + s2) = v;
        }
    }
}

// ---------------------------------------------------------------------------
extern "C" void kernel_launch(void* const* d_in, const int* in_sizes, int n_in,
                              void* d_out, int out_size, void* d_ws, size_t ws_size,
                              hipStream_t stream) {
    const float* x    = (const float*)d_in[0];
    const float* wqkv = (const float*)d_in[1];
    const float* wout = (const float*)d_in[2];
    const float* bout = (const float*)d_in[3];
    float* out = (float*)d_out;
    char* wsb  = (char*)d_ws;

    f16*   XT   = (f16*)(wsb + XT_OFF);
    f16*   QT   = (f16*)(wsb + QT_OFF);
    f16*   KT   = (f16*)(wsb + KT_OFF);
    f16*   VH   = (f16*)(wsb + VH_OFF);
    f16*   HIDT = (f16*)(wsb + HIDT_OFF);
    f16*   WQH  = (f16*)(wsb + WQH_OFF);
    f16*   WOH  = (f16*)(wsb + WOH_OFF);
    float* PART = (float*)(wsb + PART_OFF);

    wconv    <<<dim3(128), 256, 0, stream>>>(wqkv, wout, WQH, WOH);
    xpose    <<<dim3(64, 4, NB), 256, 0, stream>>>(x, XT);
    qkv_mfma <<<dim3(64, 6, NB), 256, 0, stream>>>(XT, WQH, QT, KT, VH);
    attn_mfma<<<dim3(1024), 256, 0, stream>>>(QT, KT, VH, PART);
    attn_merge<<<dim3(512), 256, 0, stream>>>(PART, HIDT);
    outp_mfma<<<dim3(64, 4, NB), 256, 0, stream>>>(HIDT, WOH, bout, out);
}

// Round 8
// 141.259 us; speedup vs baseline: 1.4430x; 1.0595x over previous
//
#include <hip/hip_runtime.h>

#define HEADS 4
#define DIM_HEAD 32
#define NB 2
#define NC 256
#define HW 4096
#define HIDDEN 128
#define NBH (NB*HEADS)
#define ROWS_TOTAL (NBH*HW)   // 32768

typedef _Float16 f16;
typedef _Float16 f16x8 __attribute__((ext_vector_type(8)));
typedef __fp16 fp16x2 __attribute__((ext_vector_type(2)));
typedef float f32x4 __attribute__((ext_vector_type(4)));

// workspace layout (bytes)
#define XT_OFF   0u                       // f16 [b][s][c256]     4 MB
#define QT_OFF   (4u<<20)                 // f16 [bh][s][d32]     2 MB
#define KT_OFF   (6u<<20)                 // f16 [bh][s][d32]     2 MB
#define VH_OFF   (8u<<20)                 // f16 [bh][d32][s]     2 MB (cols PERMUTED per 32-chunk)
#define HIDT_OFF (10u<<20)                // f16 [b][s][c128]     2 MB
#define WQH_OFF  (12u<<20)                // f16 [384][256]       192 KB
#define WOH_OFF  ((12u<<20) + (256u<<10)) // f16 [256][128]       64 KB
#define PART_OFF (13u<<20)                // f32 [split][33][32768]  13 MB (3 splits)
#define NSPLIT 3                          // 768 blocks = 3/CU exactly: ONE
                                          // full-residency generation, no tail

__device__ __forceinline__ f16x8 ldg_f16x8(const f16* p) {
    union { uint4 u; f16x8 v; } t;
    t.u = *reinterpret_cast<const uint4*>(p);
    return t.v;
}
__device__ __forceinline__ unsigned packh2(float a, float b) {
    union { fp16x2 h; unsigned u; } t;
    t.h = __builtin_amdgcn_cvt_pkrtz(a, b);
    return t.u;
}

// ---------------------------------------------------------------------------
// wconv: permute+convert weights to f16.
// ---------------------------------------------------------------------------
__global__ __launch_bounds__(256) void wconv(const float* __restrict__ wqkv,
                                             const float* __restrict__ wout,
                                             f16* __restrict__ wqh,
                                             f16* __restrict__ woh) {
    const int tid = blockIdx.x * 256 + threadIdx.x;
    const float QSCALE = 0.17677669529663687f * 1.4426950408889634f;
    if (tid < 24576) {                       // 384*256/4
        int o_lin = tid >> 6;
        int c4 = (tid & 63) * 4;
        int which = o_lin >> 7, r = o_lin & 127;
        int head = r >> 5, d = r & 31;
        int o_g = head * 96 + d * 3 + which;
        float4 v = *reinterpret_cast<const float4*>(wqkv + o_g * 256 + c4);
        float scl = (which == 0) ? QSCALE : 1.0f;
        uint2 pv;
        pv.x = packh2(v.x * scl, v.y * scl);
        pv.y = packh2(v.z * scl, v.w * scl);
        *reinterpret_cast<uint2*>(wqh + o_lin * 256 + c4) = pv;
    } else if (tid < 24576 + 8192) {         // 256*128/4
        int t2 = tid - 24576;
        float4 v = *reinterpret_cast<const float4*>(wout + t2 * 4);
        uint2 pv;
        pv.x = packh2(v.x, v.y);
        pv.y = packh2(v.z, v.w);
        *reinterpret_cast<uint2*>(woh + t2 * 4) = pv;
    }
}

// ---------------------------------------------------------------------------
// xpose: x[b][c][s] fp32 -> XT[b][s][c] f16 (64x64 LDS-transposed tiles)
// ---------------------------------------------------------------------------
__global__ __launch_bounds__(256) void xpose(const float* __restrict__ x,
                                             f16* __restrict__ xt) {
    __shared__ float T[64][65];
    const int s0 = blockIdx.x * 64, c0 = blockIdx.y * 64, b = blockIdx.z;
    const int t = threadIdx.x;
    #pragma unroll
    for (int i = 0; i < 16; ++i) {
        int e = t + i * 256;
        int c = e >> 6, s = e & 63;
        T[c][s] = x[((size_t)(b * NC + c0 + c)) * HW + s0 + s];
    }
    __syncthreads();
    const int s = t >> 2, cg = (t & 3) * 16;
    unsigned ov[8];
    #pragma unroll
    for (int i = 0; i < 8; ++i)
        ov[i] = packh2(T[cg + 2 * i][s], T[cg + 2 * i + 1][s]);
    f16* dst = xt + ((size_t)(b * HW + s0 + s)) * 256 + c0 + cg;
    *reinterpret_cast<uint4*>(dst)     = make_uint4(ov[0], ov[1], ov[2], ov[3]);
    *reinterpret_cast<uint4*>(dst + 8) = make_uint4(ov[4], ov[5], ov[6], ov[7]);
}

// ---------------------------------------------------------------------------
// qkv_mfma: C[s][o_lin] = XT * WQH^T  (f16 MFMA, K=256).
// VH columns PERMUTED within each 32-aligned chunk so attn's post-QK
// lane-resident exp values are directly the PV B-fragment.
// ---------------------------------------------------------------------------
__global__ __launch_bounds__(256) void qkv_mfma(const f16* __restrict__ xt,
                                                const f16* __restrict__ wqh,
                                                f16* __restrict__ qt,
                                                f16* __restrict__ kt,
                                                f16* __restrict__ vh) {
    const int w = threadIdx.x >> 6, lane = threadIdx.x & 63;
    const int q15 = lane & 15, quad = lane >> 4;
    const int b = blockIdx.z;
    const int sTile = blockIdx.x * 64 + (w & 1) * 32;
    const int oTile = blockIdx.y * 64 + (w >> 1) * 32;
    const f16* A = xt + ((size_t)(b * HW + sTile)) * 256;

    f32x4 acc[2][2];
    #pragma unroll
    for (int i = 0; i < 2; ++i)
        #pragma unroll
        for (int j = 0; j < 2; ++j) acc[i][j] = (f32x4){0.f, 0.f, 0.f, 0.f};

    #pragma unroll
    for (int kc = 0; kc < 256; kc += 32) {
        f16x8 a0 = ldg_f16x8(A + (size_t)q15 * 256 + kc + quad * 8);
        f16x8 a1 = ldg_f16x8(A + (size_t)(16 + q15) * 256 + kc + quad * 8);
        f16x8 b0 = ldg_f16x8(wqh + (size_t)(oTile + q15) * 256 + kc + quad * 8);
        f16x8 b1 = ldg_f16x8(wqh + (size_t)(oTile + 16 + q15) * 256 + kc + quad * 8);
        acc[0][0] = __builtin_amdgcn_mfma_f32_16x16x32_f16(a0, b0, acc[0][0], 0, 0, 0);
        acc[0][1] = __builtin_amdgcn_mfma_f32_16x16x32_f16(a0, b1, acc[0][1], 0, 0, 0);
        acc[1][0] = __builtin_amdgcn_mfma_f32_16x16x32_f16(a1, b0, acc[1][0], 0, 0, 0);
        acc[1][1] = __builtin_amdgcn_mfma_f32_16x16x32_f16(a1, b1, acc[1][1], 0, 0, 0);
    }

    #pragma unroll
    for (int si = 0; si < 2; ++si)
        #pragma unroll
        for (int oj = 0; oj < 2; ++oj) {
            int o_lin = oTile + oj * 16 + q15;
            int which = o_lin >> 7;           // wave-uniform (tiles pure)
            int r = o_lin & 127;
            int head = r >> 5, d = r & 31;
            int bh = b * HEADS + head;
            int s2 = sTile + si * 16 + quad * 4;
            if (which == 2) {
                uint2 pv;
                pv.x = packh2(acc[si][oj][0], acc[si][oj][1]);
                pv.y = packh2(acc[si][oj][2], acc[si][oj][3]);
                int vcol = sTile + quad * 8 + si * 4;
                *reinterpret_cast<uint2*>(vh + ((size_t)(bh * 32 + d)) * HW + vcol) = pv;
            } else {
                f16* dst = (which == 0 ? qt : kt) + (size_t)bh * HW * 32;
                #pragma unroll
                for (int r2 = 0; r2 < 4; ++r2)
                    dst[(size_t)(s2 + r2) * 32 + d] = (f16)acc[si][oj][r2];
            }
        }
}

// ---------------------------------------------------------------------------
// attn_mfma: MFMA flash attention, no-max softmax, split-K over j (3 splits),
// explicit next-chunk prefetch.  Per wave: 32 q-rows x split-span keys.
// Zero LDS; VH permutation makes exp values the PV B-fragment directly.
// r8 GEOMETRY FIX: r7's 1024-block grid ran as 768 resident + 256 tail on
// 1/3 of the machine (VGPR 164 -> 3 blocks/CU): total ~64xC.  NSPLIT=3 ->
// 768 blocks = exactly 3/CU = ONE full generation, splits 43/43/42 chunks:
// ~43xC.  Inner body byte-identical to the r5/r7-measured version.
// XCD-AFFINITY: 96 blocks/XCD = 3 (split,bh) combos x 32 q-blocks,
// ~384KB K/V per XCD (L2-resident; FETCH 17.5->6.3MB verified r5).
// NO launch_bounds min-occupancy arg (r2/r4: any hint -> spill storm).
// ---------------------------------------------------------------------------
__global__ __launch_bounds__(256) void attn_mfma(const f16* __restrict__ qt,
                                                 const f16* __restrict__ kt,
                                                 const f16* __restrict__ vh,
                                                 float* __restrict__ part) {
    const int w    = threadIdx.x >> 6;
    const int lane = threadIdx.x & 63;
    const int q15  = lane & 15;
    const int quad = lane >> 4;

    const int L    = blockIdx.x;          // 0..767
    const int xcd  = L & 7;               // dispatch round-robin -> XCD id
    const int slot = L >> 3;              // 0..95 within XCD
    const int combo = xcd * 3 + (slot >> 5);   // 0..23 = (split,bh)
    const int qblk  = slot & 31;
    const int bh    = combo & 7;
    const int split = combo >> 3;              // 0..2
    const int qbase = (qblk * 4 + w) * 32;

    const f16* Qb = qt + (size_t)bh * HW * 32;
    const f16* Kb = kt + (size_t)bh * HW * 32;
    const f16* Vb = vh + (size_t)bh * 32 * HW;

    f16x8 qf0 = ldg_f16x8(Qb + (size_t)(qbase + q15) * 32 + quad * 8);
    f16x8 qf1 = ldg_f16x8(Qb + (size_t)(qbase + 16 + q15) * 32 + quad * 8);

    f32x4 acc[2][2];
    #pragma unroll
    for (int a = 0; a < 2; ++a)
        #pragma unroll
        for (int b2 = 0; b2 < 2; ++b2)
            acc[a][b2] = (f32x4){0.f, 0.f, 0.f, 0.f};
    float l0 = 0.f, l1 = 0.f;

    // splits: 43/43/42 chunks of 32 keys (1376+1376+1344 = 4096)
    const int j0   = split * 1376;
    const int span = (split == 2) ? 1344 : 1376;

    f16x8 kf0 = ldg_f16x8(Kb + (size_t)(j0 + q15) * 32 + quad * 8);
    f16x8 kf1 = ldg_f16x8(Kb + (size_t)(j0 + 16 + q15) * 32 + quad * 8);
    f16x8 vf0 = ldg_f16x8(Vb + (size_t)q15 * HW + j0 + quad * 8);
    f16x8 vf1 = ldg_f16x8(Vb + (size_t)(16 + q15) * HW + j0 + quad * 8);

    for (int jc = 0; jc < span; jc += 32) {
        const int jn = j0 + jc + 32;   // prefetch (last iter reads past span:
                                       // lands in adjacent ws region, unused)
        f16x8 nk0 = ldg_f16x8(Kb + (size_t)(jn + q15) * 32 + quad * 8);
        f16x8 nk1 = ldg_f16x8(Kb + (size_t)(jn + 16 + q15) * 32 + quad * 8);
        f16x8 nv0 = ldg_f16x8(Vb + (size_t)q15 * HW + jn + quad * 8);
        f16x8 nv1 = ldg_f16x8(Vb + (size_t)(16 + q15) * HW + jn + quad * 8);

        const f32x4 z = {0.f, 0.f, 0.f, 0.f};
        #pragma unroll
        for (int qb = 0; qb < 2; ++qb) {
            f16x8 qf = qb ? qf1 : qf0;
            // s0[r] = S[key = quad*4+r][q=q15], s1[r] = S[key = 16+quad*4+r][q]
            f32x4 s0 = __builtin_amdgcn_mfma_f32_16x16x32_f16(kf0, qf, z, 0, 0, 0);
            f32x4 s1 = __builtin_amdgcn_mfma_f32_16x16x32_f16(kf1, qf, z, 0, 0, 0);
            float e[8];
            #pragma unroll
            for (int r = 0; r < 4; ++r) {
                e[r]     = __builtin_amdgcn_exp2f(s0[r]);
                e[4 + r] = __builtin_amdgcn_exp2f(s1[r]);
            }
            float ls = (e[0] + e[1]) + (e[2] + e[3]) + (e[4] + e[5]) + (e[6] + e[7]);
            if (qb) l1 += ls; else l0 += ls;
            // VH column permutation makes this lane's 8 exp values exactly
            // B[k = quad*8 + 0..7][q=q15] for the PV MFMA: pack and go.
            union { unsigned u[4]; f16x8 v; } pu;
            pu.u[0] = packh2(e[0], e[1]);
            pu.u[1] = packh2(e[2], e[3]);
            pu.u[2] = packh2(e[4], e[5]);
            pu.u[3] = packh2(e[6], e[7]);
            acc[qb][0] = __builtin_amdgcn_mfma_f32_16x16x32_f16(vf0, pu.v, acc[qb][0], 0, 0, 0);
            acc[qb][1] = __builtin_amdgcn_mfma_f32_16x16x32_f16(vf1, pu.v, acc[qb][1], 0, 0, 0);
        }
        kf0 = nk0; kf1 = nk1; vf0 = nv0; vf1 = nv1;
    }

    float* P = part + (size_t)split * 33 * ROWS_TOTAL;
    #pragma unroll
    for (int qb = 0; qb < 2; ++qb) {
        float lv = qb ? l1 : l0;
        lv += __shfl_xor(lv, 16, 64);
        lv += __shfl_xor(lv, 32, 64);
        const int grow = bh * HW + qbase + qb * 16 + q15;
        if (quad == 0) P[grow] = lv;
        #pragma unroll
        for (int t = 0; t < 2; ++t)
            #pragma unroll
            for (int r = 0; r < 4; ++r) {
                int d = t * 16 + quad * 4 + r;
                P[(size_t)(1 + d) * ROWS_TOTAL + grow] = acc[qb][t][r];
            }
    }
}

// ---------------------------------------------------------------------------
// attn_merge: sum NSPLIT additive splits, normalize, write HIDT f16.
// thread = (grow, dquad): 131072 threads / 512 blocks, 27 independent 4B
// loads + one coalesced 16B write each (r7 fix: was 64us at 128 blocks).
// ---------------------------------------------------------------------------
__global__ __launch_bounds__(256) void attn_merge(const float* __restrict__ part,
                                                  f16* __restrict__ hidt) {
    const int t = blockIdx.x * 256 + threadIdx.x;      // 0..131071
    const int grow = t >> 2;                           // 0..32767
    const int dq   = t & 3;                            // 0..3 (8 d values each)
    float l = 0.f;
    #pragma unroll
    for (int sp = 0; sp < NSPLIT; ++sp)
        l += part[(size_t)sp * 33 * ROWS_TOTAL + grow];
    const float inv = 1.0f / l;
    const int bh = grow >> 12, s = grow & 4095;
    const int b = bh >> 2, h = bh & 3;

    unsigned ov[4];
    #pragma unroll
    for (int i = 0; i < 4; ++i) {
        const int d2 = dq * 4 + i;
        float o0 = 0.f, o1 = 0.f;
        #pragma unroll
        for (int sp = 0; sp < NSPLIT; ++sp) {
            const float* P = part + (size_t)sp * 33 * ROWS_TOTAL + grow;
            o0 += P[(size_t)(1 + 2 * d2) * ROWS_TOTAL];
            o1 += P[(size_t)(2 + 2 * d2) * ROWS_TOTAL];
        }
        ov[i] = packh2(o0 * inv, o1 * inv);
    }
    f16* dst = hidt + ((size_t)(b * HW + s)) * 128 + h * 32 + dq * 8;
    *reinterpret_cast<uint4*>(dst) = make_uint4(ov[0], ov[1], ov[2], ov[3]);
}

// ---------------------------------------------------------------------------
// outp_mfma: out[b][o][s] = HIDT * WOH^T + bias  (f16 MFMA, K=128, fp32 out)
// ---------------------------------------------------------------------------
__global__ __launch_bounds__(256) void outp_mfma(const f16* __restrict__ hidt,
                                                 const f16* __restrict__ woh,
                                                 const float* __restrict__ bout,
                                                 float* __restrict__ out) {
    const int w = threadIdx.x >> 6, lane = threadIdx.x & 63;
    const int q15 = lane & 15, quad = lane >> 4;
    const int b = blockIdx.z;
    const int sTile = blockIdx.x * 64 + (w & 1) * 32;
    const int oTile = blockIdx.y * 64 + (w >> 1) * 32;
    const f16* A = hidt + ((size_t)(b * HW + sTile)) * 128;

    f32x4 acc[2][2];
    #pragma unroll
    for (int i = 0; i < 2; ++i)
        #pragma unroll
        for (int j = 0; j < 2; ++j) acc[i][j] = (f32x4){0.f, 0.f, 0.f, 0.f};

    #pragma unroll
    for (int kc = 0; kc < 128; kc += 32) {
        f16x8 a0 = ldg_f16x8(A + (size_t)q15 * 128 + kc + quad * 8);
        f16x8 a1 = ldg_f16x8(A + (size_t)(16 + q15) * 128 + kc + quad * 8);
        f16x8 b0 = ldg_f16x8(woh + (size_t)(oTile + q15) * 128 + kc + quad * 8);
        f16x8 b1 = ldg_f16x8(woh + (size_t)(oTile + 16 + q15) * 128 + kc + quad * 8);
        acc[0][0] = __builtin_amdgcn_mfma_f32_16x16x32_f16(a0, b0, acc[0][0], 0, 0, 0);
        acc[0][1] = __builtin_amdgcn_mfma_f32_16x16x32_f16(a0, b1, acc[0][1], 0, 0, 0);
        acc[1][0] = __builtin_amdgcn_mfma_f32_16x16x32_f16(a1, b0, acc[1][0], 0, 0, 0);
        acc[1][1] = __builtin_amdgcn_mfma_f32_16x16x32_f16(a1, b1, acc[1][1], 0, 0, 0);
    }

    #pragma unroll
    for (int oj = 0; oj < 2; ++oj) {
        const int o = oTile + oj * 16 + q15;
        const float bias = bout[o];
        #pragma unroll
        for (int si = 0; si < 2; ++si) {
            const int s2 = sTile + si * 16 + quad * 4;
            float4 v = make_float4(acc[si][oj][0] + bias, acc[si][oj][1] + bias,
                                   acc[si][oj][2] + bias, acc[si][oj][3] + bias);
            *reinterpret_cast<float4*>(out + ((size_t)(b * NC + o)) * HW + s2) = v;
        }
    }
}

// ---------------------------------------------------------------------------
extern "C" void kernel_launch(void* const* d_in, const int* in_sizes, int n_in,
                              void* d_out, int out_size, void* d_ws, size_t ws_size,
                              hipStream_t stream) {
    const float* x    = (const float*)d_in[0];
    const float* wqkv = (const float*)d_in[1];
    const float* wout = (const float*)d_in[2];
    const float* bout = (const float*)d_in[3];
    float* out = (float*)d_out;
    char* wsb  = (char*)d_ws;

    f16*   XT   = (f16*)(wsb + XT_OFF);
    f16*   QT   = (f16*)(wsb + QT_OFF);
    f16*   KT   = (f16*)(wsb + KT_OFF);
    f16*   VH   = (f16*)(wsb + VH_OFF);
    f16*   HIDT = (f16*)(wsb + HIDT_OFF);
    f16*   WQH  = (f16*)(wsb + WQH_OFF);
    f16*   WOH  = (f16*)(wsb + WOH_OFF);
    float* PART = (float*)(wsb + PART_OFF);

    wconv    <<<dim3(128), 256, 0, stream>>>(wqkv, wout, WQH, WOH);
    xpose    <<<dim3(64, 4, NB), 256, 0, stream>>>(x, XT);
    qkv_mfma <<<dim3(64, 6, NB), 256, 0, stream>>>(XT, WQH, QT, KT, VH);
    attn_mfma<<<dim3(768), 256, 0, stream>>>(QT, KT, VH, PART);
    attn_merge<<<dim3(512), 256, 0, stream>>>(PART, HIDT);
    outp_mfma<<<dim3(64, 4, NB), 256, 0, stream>>>(HIDT, WOH, bout, out);
}